// Round 3
// baseline (831.261 us; speedup 1.0000x reference)
//
#include <hip/hip_runtime.h>

#define HALO 10
#define NT 64          // threads per block = 1 wave; strip width = 64 output cols
#define SWD 76         // staged row width (74 used, padded even)

typedef float v2f __attribute__((ext_vector_type(2)));

__device__ __forceinline__ void make_gauss(float* g) {
    float s = 0.f;
#pragma unroll
    for (int i = 0; i < 11; ++i) {
        float d = (float)(i - 5);
        g[i] = expf(-d * d / 4.5f);   // sigma=1.5 -> 2*sigma^2 = 4.5
        s += g[i];
    }
    float inv = 1.f / s;
#pragma unroll
    for (int i = 0; i < 11; ++i) g[i] *= inv;
}

// Row-streaming separable SSIM, single-wave blocks (no inter-wave barriers).
// One thread per output column (64-col strip). Vertical conv in 55 register
// accumulators; depth-2 software-pipelined global loads; 2x2 avg-pool to the
// next pyramid level fused in (rows i-1,i both live in the double buffer).
__global__ __launch_bounds__(64, 3) void ssim_fused_kernel(
    const float* __restrict__ x, const float* __restrict__ y,
    float* __restrict__ xo, float* __restrict__ yo,
    float* __restrict__ acc, int H, int W, int ROWS, int do_pool)
{
    const int OH = H - HALO, OW = W - HALO;
    const int nc = blockIdx.z;
    const int col0 = blockIdx.x * NT;
    const int r0 = blockIdx.y * ROWS;
    const int tid = threadIdx.x;

    const int c = col0 + tid;
    const bool colvalid = (c < OW);
    const int cl = min(c, W - 1);                 // clamped main col
    const int chalo = min(col0 + NT + tid, W - 1); // clamped halo col (tid<10)

    const int n_out = max(0, min(ROWS, OH - r0));
    const int poolrows = do_pool ? min(ROWS, H - r0) : 0;
    const int n_iter = max(n_out > 0 ? n_out + HALO : 0, poolrows);

    const float* xp = x + (size_t)nc * H * W;
    const float* yp = y + (size_t)nc * H * W;

    __shared__ float sA[2][SWD];
    __shared__ float sB[2][SWD];

    float g[11];
    make_gauss(g);

    // parity-adjusted 12-tap weights (even tid reads [t..t+11], odd [t-1..t+10])
    float w2[12];
    const int par = tid & 1;
#pragma unroll
    for (int s = 0; s < 12; ++s) {
        float ge = (s < 11) ? g[s] : 0.f;
        float go = (s > 0) ? g[s - 1] : 0.f;
        w2[s] = par ? go : ge;
    }
    const int e = tid & ~1;

    // vertical accumulators: 11 rotating slots x {mean2, sq2, cross}
    v2f accm[11], accs[11];
    float accc[11];
#pragma unroll
    for (int k = 0; k < 11; ++k) { accm[k] = 0.f; accs[k] = 0.f; accc[k] = 0.f; }

    float ssim_sum = 0.f, cs_sum = 0.f;

    // two in-flight register row-sets (depth-2 pipeline)
    float mxv[2], myv[2], hxv[2], hyv[2];

    auto issue = [&](int i, int s) {
        const int gr = min(r0 + i, H - 1);
        const size_t rb = (size_t)gr * W;
        mxv[s] = xp[rb + cl];
        myv[s] = yp[rb + cl];
        if (tid < HALO) { hxv[s] = xp[rb + chalo]; hyv[s] = yp[rb + chalo]; }
    };
    auto stage = [&](int s, int p) {
        sA[p][tid] = mxv[s]; sB[p][tid] = myv[s];
        if (tid < HALO) { sA[p][NT + tid] = hxv[s]; sB[p][NT + tid] = hyv[s]; }
    };

    if (n_iter > 0) {
        // prologue: buf0 <- row0; row1,row2 in flight
        issue(0, 0);
        issue(1, 1);
        stage(0, 0);
        issue(2, 0);

        const int NI = ((n_iter + 10) / 11) * 11;
        for (int ii = 0; ii < NI; ii += 11) {
#pragma unroll
            for (int u = 0; u < 11; ++u) {
                const int i = ii + u;
                const int p = i & 1, q = p ^ 1;

                // fused 2x2 avg-pool: rows i-1 (buf q) and i (buf p), before
                // buf q is overwritten with row i+1
                if (p == 1 && i < poolrows && do_pool && tid < 32) {
                    const float2 xa = *(const float2*)&sA[0][2 * tid];
                    const float2 xb = *(const float2*)&sA[1][2 * tid];
                    const float2 ya = *(const float2*)&sB[0][2 * tid];
                    const float2 yb = *(const float2*)&sB[1][2 * tid];
                    const int pr = (r0 + i) >> 1;
                    const size_t ob = (size_t)nc * (H >> 1) * (W >> 1)
                                    + (size_t)pr * (W >> 1) + (col0 >> 1) + tid;
                    xo[ob] = 0.25f * (xa.x + xa.y + xb.x + xb.y);
                    yo[ob] = 0.25f * (ya.x + ya.y + yb.x + yb.y);
                }

                // stage row i+1 (loaded 2 iters ago), then issue row i+3
                stage(q, q);
                issue(i + 3, q);

                // horizontal 11-tap conv of row i from buf p (aligned float2)
                const v2f* pa = (const v2f*)&sA[p][e];
                const v2f* pb = (const v2f*)&sB[p][e];
                v2f m = 0.f, sq = 0.f;
                float cr = 0.f;
#pragma unroll
                for (int k2 = 0; k2 < 6; ++k2) {
                    const v2f qa = pa[k2], qb = pb[k2];
                    const float w0 = w2[2 * k2], w1 = w2[2 * k2 + 1];
                    v2f t0; t0.x = qa.x; t0.y = qb.x;
                    m += t0 * w0;
                    sq += (t0 * t0) * w0;
                    cr += qa.x * qb.x * w0;
                    v2f t1; t1.x = qa.y; t1.y = qb.y;
                    m += t1 * w1;
                    sq += (t1 * t1) * w1;
                    cr += qa.y * qb.y * w1;
                }

                // vertical accumulate into 11 rotating slots
#pragma unroll
                for (int k = 0; k < 11; ++k) {
                    const float w = g[(u - k + 11) % 11];
                    accm[k] += m * w;
                    accs[k] += sq * w;
                    accc[k] += cr * w;
                }

                // slot (u+1)%11 completed output row o = i-10
                const int kc = (u + 1) % 11;
                const int o = i - HALO;
                if (o >= 0 && o < n_out && colvalid) {
                    const float mx = accm[kc].x, my = accm[kc].y;
                    const float mxx = accs[kc].x, myy = accs[kc].y, mxy = accc[kc];
                    const float mu_x2 = mx * mx, mu_y2 = my * my, mu_xy = mx * my;
                    const float sxq = mxx - mu_x2, syq = myy - mu_y2, sxyv = mxy - mu_xy;
                    const float c1 = 1e-4f, c2 = 9e-4f;
                    const float cs = (2.f * sxyv + c2) * __builtin_amdgcn_rcpf(sxq + syq + c2);
                    const float ssim = (2.f * mu_xy + c1) * __builtin_amdgcn_rcpf(mu_x2 + mu_y2 + c1) * cs;
                    ssim_sum += ssim;
                    cs_sum += cs;
                }
                accm[kc] = 0.f; accs[kc] = 0.f; accc[kc] = 0.f;
            }
        }
    }

    // single-wave reduction + one atomic pair per block
#pragma unroll
    for (int off = 32; off > 0; off >>= 1) {
        ssim_sum += __shfl_down(ssim_sum, off, 64);
        cs_sum   += __shfl_down(cs_sum,   off, 64);
    }
    if (tid == 0) {
        atomicAdd(&acc[nc * 2 + 0], ssim_sum);
        atomicAdd(&acc[nc * 2 + 1], cs_sum);
    }
}

// Combine the 5 scales: prod_s val_s^{w_s}, mean over the 48 (n,c) pairs.
__global__ void finalize_kernel(const float* __restrict__ acc,
                                const float* __restrict__ weights,
                                float* __restrict__ out)
{
    int t = threadIdx.x;  // 64 threads
    float v = 0.f;
    if (t < 48) {
        float prod = 1.f;
#pragma unroll
        for (int s = 0; s < 5; ++s) {
            int O = (512 >> s) - HALO;
            float inv = 1.f / ((float)O * (float)O);
            float ssim = acc[s * 96 + t * 2 + 0] * inv;
            float cs   = acc[s * 96 + t * 2 + 1] * inv;
            float val = (s < 4) ? fmaxf(cs, 0.f) : ssim;  // mcs[:-1] + [ssim]
            prod *= powf(val, weights[s]);
        }
        v = prod;
    }
#pragma unroll
    for (int off = 32; off > 0; off >>= 1) v += __shfl_down(v, off, 64);
    if (t == 0) out[0] = v * (1.f / 48.f);
}

extern "C" void kernel_launch(void* const* d_in, const int* in_sizes, int n_in,
                              void* d_out, int out_size, void* d_ws, size_t ws_size,
                              hipStream_t stream) {
    const float* x = (const float*)d_in[0];       // (16,3,512,512)
    const float* y = (const float*)d_in[1];       // (16,3,512,512)
    const float* weights = (const float*)d_in[3]; // (5,)
    float* out = (float*)d_out;
    float* ws = (float*)d_ws;

    // workspace layout (floats):
    //   [0,480)   : acc[5 scales][48 nc][2]   (ssim_sum, cs_sum)
    //   [512, ..) : downsampled pyramid x/y per scale
    float* acc = ws;
    float* xs1 = ws + 512;
    float* ys1 = xs1 + (size_t)48 * 256 * 256;
    float* xs2 = ys1 + (size_t)48 * 256 * 256;
    float* ys2 = xs2 + (size_t)48 * 128 * 128;
    float* xs3 = ys2 + (size_t)48 * 128 * 128;
    float* ys3 = xs3 + (size_t)48 * 64 * 64;
    float* xs4 = ys3 + (size_t)48 * 64 * 64;
    float* ys4 = xs4 + (size_t)48 * 32 * 32;

    hipMemsetAsync(acc, 0, 480 * sizeof(float), stream);

    dim3 blk(NT);
    // scale 0: 512x512, strips=8, chunks of 64 rows -> 3072 blocks
    ssim_fused_kernel<<<dim3(8, 8, 48), blk, 0, stream>>>(x, y, xs1, ys1, acc + 0 * 96, 512, 512, 64, 1);
    // scale 1: 256x256, strips=4, chunks of 64 -> 768 blocks
    ssim_fused_kernel<<<dim3(4, 4, 48), blk, 0, stream>>>(xs1, ys1, xs2, ys2, acc + 1 * 96, 256, 256, 64, 1);
    // scale 2: 128x128, strips=2, chunks of 16 -> 768 blocks
    ssim_fused_kernel<<<dim3(2, 8, 48), blk, 0, stream>>>(xs2, ys2, xs3, ys3, acc + 2 * 96, 128, 128, 16, 1);
    // scale 3: 64x64, strips=1, chunks of 8 -> 384 blocks
    ssim_fused_kernel<<<dim3(1, 8, 48), blk, 0, stream>>>(xs3, ys3, xs4, ys4, acc + 3 * 96, 64, 64, 8, 1);
    // scale 4: 32x32, strips=1, chunks of 8 -> 192 blocks, no pooling
    ssim_fused_kernel<<<dim3(1, 4, 48), blk, 0, stream>>>(xs4, ys4, nullptr, nullptr, acc + 4 * 96, 32, 32, 8, 0);

    finalize_kernel<<<dim3(1), dim3(64), 0, stream>>>(acc, weights, out);
}

// Round 4
// 708.807 us; speedup vs baseline: 1.1728x; 1.1728x over previous
//
#include <hip/hip_runtime.h>

#define HALO 10
#define SWD 76   // per-wave staged row width (74 used, padded even)

typedef float v2f __attribute__((ext_vector_type(2)));

__device__ __forceinline__ void make_gauss(float* g) {
    float s = 0.f;
#pragma unroll
    for (int i = 0; i < 11; ++i) {
        float d = (float)(i - 5);
        g[i] = expf(-d * d / 4.5f);   // sigma=1.5 -> 2*sigma^2 = 4.5
        s += g[i];
    }
    float inv = 1.f / s;
#pragma unroll
    for (int i = 0; i < 11; ++i) g[i] *= inv;
}

// Wave-private row-streaming separable SSIM + fused 2x2 avg-pool.
// 256-thr blocks, ZERO __syncthreads: each wave owns a 64-col strip x ROWS
// row-chunk, stages rows in its own LDS slice (within-wave DS ordering needs
// no barrier). Depth-1 prefetch in SCALAR regs (no runtime-indexed register
// arrays -> no scratch spill). Vertical conv in 11 rotating static slots.
__global__ __launch_bounds__(256, 3) void ssim_wave_kernel(
    const float* __restrict__ x, const float* __restrict__ y,
    float* __restrict__ xo, float* __restrict__ yo,
    float* __restrict__ acc, int H, int W, int ROWS, int do_pool)
{
    const int OH = H - HALO, OW = W - HALO;
    const int nc = blockIdx.z;
    const int tid = threadIdx.x;
    const int wave = tid >> 6, lane = tid & 63;
    const int col0 = blockIdx.x * 64;
    const int r0 = (blockIdx.y * 4 + wave) * ROWS;

    const int c = col0 + lane;
    const bool colvalid = (c < OW);
    const int cl = min(c, W - 1);                   // clamped main col
    const int chalo = min(col0 + 64 + lane, W - 1); // clamped halo col (lane<10)

    const int n_out = min(ROWS, OH - r0);                     // may be <= 0
    const int poolrows = do_pool ? min(ROWS, H - r0) : 0;
    const int n_iter = max(n_out > 0 ? n_out + HALO : 0, poolrows);

    const float* xp = x + (size_t)nc * H * W;
    const float* yp = y + (size_t)nc * H * W;

    __shared__ float sA[4][SWD];
    __shared__ float sB[4][SWD];
    float* myA = sA[wave];
    float* myB = sB[wave];

    float g[11];
    make_gauss(g);

    // parity-adjusted 12-tap weights (even lane reads [t..t+11], odd [t-1..t+10])
    float w2[12];
    const int par = lane & 1;
#pragma unroll
    for (int s = 0; s < 12; ++s) {
        float ge = (s < 11) ? g[s] : 0.f;
        float go = (s > 0) ? g[s - 1] : 0.f;
        w2[s] = par ? go : ge;
    }
    const int e = lane & ~1;

    // vertical accumulators: 11 rotating slots x {packed means, packed squares, cross}
    v2f accm[11], accs[11];
    float accc[11];
#pragma unroll
    for (int k = 0; k < 11; ++k) {
        accm[k] = (v2f){0.f, 0.f}; accs[k] = (v2f){0.f, 0.f}; accc[k] = 0.f;
    }

    float ssim_sum = 0.f, cs_sum = 0.f;

    // depth-1 prefetch: SCALAR registers only (never runtime-indexed)
    float vx = 0.f, vy = 0.f, hxv = 0.f, hyv = 0.f;
    float prevx = 0.f, prevy = 0.f;

    const int Wo = W >> 1;
    float* xop = xo + (size_t)nc * (H >> 1) * Wo + (col0 >> 1);
    float* yop = yo + (size_t)nc * (H >> 1) * Wo + (col0 >> 1);

    if (n_iter > 0) {
        {   // load row 0 (r0 < H always by grid construction)
            const float* rx = xp + (size_t)r0 * W;
            const float* ry = yp + (size_t)r0 * W;
            vx = rx[cl]; vy = ry[cl];
            if (lane < HALO) { hxv = rx[chalo]; hyv = ry[chalo]; }
        }
        const int NI = ((n_iter + 10) / 11) * 11;
        for (int ii = 0; ii < NI; ii += 11) {
#pragma unroll
            for (int u = 0; u < 11; ++u) {
                const int i = ii + u;

                // fused 2x2 avg-pool straight from the row registers
                if (do_pool && i < poolrows) {
                    float sx2 = vx + __shfl_xor(vx, 1, 64);
                    float sy2 = vy + __shfl_xor(vy, 1, 64);
                    if (i & 1) {
                        if (par == 0) {
                            const int pr = (r0 + i) >> 1;
                            xop[(size_t)pr * Wo + (lane >> 1)] = 0.25f * (prevx + sx2);
                            yop[(size_t)pr * Wo + (lane >> 1)] = 0.25f * (prevy + sy2);
                        }
                    } else { prevx = sx2; prevy = sy2; }
                }

                // stage row i into this wave's LDS slice (no barrier needed)
                myA[lane] = vx; myB[lane] = vy;
                if (lane < HALO) { myA[64 + lane] = hxv; myB[64 + lane] = hyv; }

                // issue loads for row i+1 (consumed next iteration)
                {
                    const int rr = min(r0 + i + 1, H - 1);
                    const float* rx = xp + (size_t)rr * W;
                    const float* ry = yp + (size_t)rr * W;
                    vx = rx[cl]; vy = ry[cl];
                    if (lane < HALO) { hxv = rx[chalo]; hyv = ry[chalo]; }
                }

                // horizontal 11-tap conv via aligned float2 LDS reads
                const v2f* pa = (const v2f*)&myA[e];
                const v2f* pb = (const v2f*)&myB[e];
                v2f m = {0.f, 0.f}, sq = {0.f, 0.f};
                float cr = 0.f;
#pragma unroll
                for (int k2 = 0; k2 < 6; ++k2) {
                    const v2f qa = pa[k2], qb = pb[k2];
                    {
                        const float w = w2[2 * k2];
                        v2f p = {qa.x, qb.x};
                        m += p * w; sq += (p * p) * w; cr += qa.x * qb.x * w;
                    }
                    {
                        const float w = w2[2 * k2 + 1];
                        v2f p = {qa.y, qb.y};
                        m += p * w; sq += (p * p) * w; cr += qa.y * qb.y * w;
                    }
                }

                // vertical accumulate into the 11 rotating slots (static idx)
#pragma unroll
                for (int k = 0; k < 11; ++k) {
                    const float w = g[(u - k + 11) % 11];
                    accm[k] += m * w;
                    accs[k] += sq * w;
                    accc[k] += cr * w;
                }

                // slot (u+1)%11 completed output row o = i-10
                const int kc = (u + 1) % 11;
                const int o = i - HALO;
                if (o >= 0 && o < n_out && colvalid) {
                    const float mx = accm[kc].x, my = accm[kc].y;
                    const float mxx = accs[kc].x, myy = accs[kc].y, mxy = accc[kc];
                    const float mu_x2 = mx * mx, mu_y2 = my * my, mu_xy = mx * my;
                    const float sxq = mxx - mu_x2, syq = myy - mu_y2, sxyv = mxy - mu_xy;
                    const float c1 = 1e-4f, c2 = 9e-4f;
                    const float cs = (2.f * sxyv + c2) * __builtin_amdgcn_rcpf(sxq + syq + c2);
                    const float ssim = (2.f * mu_xy + c1) * __builtin_amdgcn_rcpf(mu_x2 + mu_y2 + c1) * cs;
                    ssim_sum += ssim;
                    cs_sum += cs;
                }
                accm[kc] = (v2f){0.f, 0.f};
                accs[kc] = (v2f){0.f, 0.f};
                accc[kc] = 0.f;
            }
        }
    }

    // wave-local reduction + one atomic pair per wave
#pragma unroll
    for (int off = 32; off > 0; off >>= 1) {
        ssim_sum += __shfl_down(ssim_sum, off, 64);
        cs_sum   += __shfl_down(cs_sum,   off, 64);
    }
    if (lane == 0) {
        atomicAdd(&acc[nc * 2 + 0], ssim_sum);
        atomicAdd(&acc[nc * 2 + 1], cs_sum);
    }
}

// Combine the 5 scales: prod_s val_s^{w_s}, mean over the 48 (n,c) pairs.
__global__ void finalize_kernel(const float* __restrict__ acc,
                                const float* __restrict__ weights,
                                float* __restrict__ out)
{
    int t = threadIdx.x;  // 64 threads
    float v = 0.f;
    if (t < 48) {
        float prod = 1.f;
#pragma unroll
        for (int s = 0; s < 5; ++s) {
            int O = (512 >> s) - HALO;
            float inv = 1.f / ((float)O * (float)O);
            float ssim = acc[s * 96 + t * 2 + 0] * inv;
            float cs   = acc[s * 96 + t * 2 + 1] * inv;
            float val = (s < 4) ? fmaxf(cs, 0.f) : ssim;  // mcs[:-1] + [ssim]
            prod *= powf(val, weights[s]);
        }
        v = prod;
    }
#pragma unroll
    for (int off = 32; off > 0; off >>= 1) v += __shfl_down(v, off, 64);
    if (t == 0) out[0] = v * (1.f / 48.f);
}

extern "C" void kernel_launch(void* const* d_in, const int* in_sizes, int n_in,
                              void* d_out, int out_size, void* d_ws, size_t ws_size,
                              hipStream_t stream) {
    const float* x = (const float*)d_in[0];       // (16,3,512,512)
    const float* y = (const float*)d_in[1];       // (16,3,512,512)
    const float* weights = (const float*)d_in[3]; // (5,)
    float* out = (float*)d_out;
    float* ws = (float*)d_ws;

    // workspace layout (floats):
    //   [0,480)   : acc[5 scales][48 nc][2]   (ssim_sum, cs_sum)
    //   [512, ..) : downsampled pyramid x/y per scale
    float* acc = ws;
    float* xs1 = ws + 512;
    float* ys1 = xs1 + (size_t)48 * 256 * 256;
    float* xs2 = ys1 + (size_t)48 * 256 * 256;
    float* ys2 = xs2 + (size_t)48 * 128 * 128;
    float* xs3 = ys2 + (size_t)48 * 128 * 128;
    float* ys3 = xs3 + (size_t)48 * 64 * 64;
    float* xs4 = ys3 + (size_t)48 * 64 * 64;
    float* ys4 = xs4 + (size_t)48 * 32 * 32;

    hipMemsetAsync(acc, 0, 480 * sizeof(float), stream);

    dim3 blk(256);
    // grid: (col strips of 64, row chunks of 4*ROWS, nc); 4 waves/block
    // scale 0: 512 -> 8 strips x 2 chunks (ROWS=64) = 768 blocks
    ssim_wave_kernel<<<dim3(8, 2, 48), blk, 0, stream>>>(x, y, xs1, ys1, acc + 0 * 96, 512, 512, 64, 1);
    // scale 1: 256 -> 4 x 2 (ROWS=32) = 384 blocks
    ssim_wave_kernel<<<dim3(4, 2, 48), blk, 0, stream>>>(xs1, ys1, xs2, ys2, acc + 1 * 96, 256, 256, 32, 1);
    // scale 2: 128 -> 2 x 2 (ROWS=16) = 192 blocks
    ssim_wave_kernel<<<dim3(2, 2, 48), blk, 0, stream>>>(xs2, ys2, xs3, ys3, acc + 2 * 96, 128, 128, 16, 1);
    // scale 3: 64 -> 1 x 2 (ROWS=8) = 96 blocks
    ssim_wave_kernel<<<dim3(1, 2, 48), blk, 0, stream>>>(xs3, ys3, xs4, ys4, acc + 3 * 96, 64, 64, 8, 1);
    // scale 4: 32 -> 1 x 1 (ROWS=8) = 48 blocks, no pooling
    ssim_wave_kernel<<<dim3(1, 1, 48), blk, 0, stream>>>(xs4, ys4, nullptr, nullptr, acc + 4 * 96, 32, 32, 8, 0);

    finalize_kernel<<<dim3(1), dim3(64), 0, stream>>>(acc, weights, out);
}

// Round 5
// 286.124 us; speedup vs baseline: 2.9052x; 2.4773x over previous
//
#include <hip/hip_runtime.h>

#define HALO 10
#define SWD 76   // per-wave staged row width (74 used, padded even)

typedef float v2f __attribute__((ext_vector_type(2)));

// 1D Gaussian, sigma=1.5, 11 taps, normalized (compile-time constants;
// matches the reference's fp32 window to ~1e-7 -- far under threshold)
#define G0 0.00102838f
#define G1 0.00759871f
#define G2 0.03600077f
#define G3 0.10936069f
#define G4 0.21300556f
#define G5 0.26601176f
#define G6 G4
#define G7 G3
#define G8 G2
#define G9 G1
#define G10 G0

// one horizontal tap-pair: packed {x,y} means, squares, and cross term
#define HT(QA, QB, W0, W1)                                          \
    { v2f p0; p0.x = QA.x; p0.y = QB.x;                              \
      hm += p0 * (W0); hs += p0 * p0 * (W0); hc += QA.x * QB.x * (W0);\
      v2f p1; p1.x = QA.y; p1.y = QB.y;                              \
      hm += p1 * (W1); hs += p1 * p1 * (W1); hc += QA.y * QB.y * (W1); }

// Wave-private row-streaming separable SSIM + fused 2x2 avg-pool.
// ZERO local arrays in the hot path (SROA runs before unroll: any
// runtime-indexed local array gets demoted to scratch -- R3/R4 lesson).
// Vertical 11-tap conv is a 55-scalar named shift register.
__global__ __launch_bounds__(256, 3) void ssim_wave_kernel(
    const float* __restrict__ x, const float* __restrict__ y,
    float* __restrict__ xo, float* __restrict__ yo,
    float* __restrict__ acc, int H, int W, int ROWS, int do_pool)
{
    const int OH = H - HALO, OW = W - HALO;
    const int nc = blockIdx.z;
    const int tid = threadIdx.x;
    const int wave = tid >> 6, lane = tid & 63;
    const int col0 = blockIdx.x * 64;
    const int r0 = (blockIdx.y * 4 + wave) * ROWS;

    const int c = col0 + lane;
    const bool colvalid = (c < OW);
    const int cl = min(c, W - 1);
    const int chalo = min(col0 + 64 + lane, W - 1);

    const int n_out = min(ROWS, OH - r0);
    const int poolrows = do_pool ? min(ROWS, H - r0) : 0;
    const int n_iter = max(n_out > 0 ? n_out + HALO : 0, poolrows);

    const float* xp = x + (size_t)nc * H * W;
    const float* yp = y + (size_t)nc * H * W;

    __shared__ float sA[4][SWD];
    __shared__ float sB[4][SWD];
    float* myA = sA[wave];
    float* myB = sB[wave];

    // parity-adjusted 12-tap weights as NAMED scalars
    const int par = lane & 1;
    const float w2_0  = par ? 0.f : G0;
    const float w2_1  = par ? G0  : G1;
    const float w2_2  = par ? G1  : G2;
    const float w2_3  = par ? G2  : G3;
    const float w2_4  = par ? G3  : G4;
    const float w2_5  = par ? G4  : G5;
    const float w2_6  = par ? G5  : G6;
    const float w2_7  = par ? G6  : G7;
    const float w2_8  = par ? G7  : G8;
    const float w2_9  = par ? G8  : G9;
    const float w2_10 = par ? G9  : G10;
    const float w2_11 = par ? G10 : 0.f;
    const int e = lane & ~1;

    // vertical shift register: slot j holds h-values of input row o+j
    v2f Hm0={0.f,0.f}, Hm1=Hm0, Hm2=Hm0, Hm3=Hm0, Hm4=Hm0, Hm5=Hm0,
        Hm6=Hm0, Hm7=Hm0, Hm8=Hm0, Hm9=Hm0, Hm10=Hm0;
    v2f Hs0=Hm0, Hs1=Hm0, Hs2=Hm0, Hs3=Hm0, Hs4=Hm0, Hs5=Hm0,
        Hs6=Hm0, Hs7=Hm0, Hs8=Hm0, Hs9=Hm0, Hs10=Hm0;
    float Hc0=0.f, Hc1=0.f, Hc2=0.f, Hc3=0.f, Hc4=0.f, Hc5=0.f,
          Hc6=0.f, Hc7=0.f, Hc8=0.f, Hc9=0.f, Hc10=0.f;

    float ssim_sum = 0.f, cs_sum = 0.f;

    // depth-1 prefetch, scalar registers only
    float vx = 0.f, vy = 0.f, hxv = 0.f, hyv = 0.f;
    float prevx = 0.f, prevy = 0.f;

    const int Wo = W >> 1;
    float* xop = xo + (size_t)nc * (H >> 1) * Wo + (col0 >> 1);
    float* yop = yo + (size_t)nc * (H >> 1) * Wo + (col0 >> 1);

    if (n_iter > 0) {
        {   // load row 0
            const float* rx = xp + (size_t)r0 * W;
            const float* ry = yp + (size_t)r0 * W;
            vx = rx[cl]; vy = ry[cl];
            if (lane < HALO) { hxv = rx[chalo]; hyv = ry[chalo]; }
        }
        const int NI = ((n_iter + 10) / 11) * 11;
        for (int ii = 0; ii < NI; ii += 11) {
#pragma unroll
            for (int u = 0; u < 11; ++u) {
                const int i = ii + u;

                // fused 2x2 avg-pool from the row registers
                if (do_pool && i < poolrows) {
                    float sx2 = vx + __shfl_xor(vx, 1, 64);
                    float sy2 = vy + __shfl_xor(vy, 1, 64);
                    if (i & 1) {
                        if (par == 0) {
                            const int pr = (r0 + i) >> 1;
                            xop[(size_t)pr * Wo + (lane >> 1)] = 0.25f * (prevx + sx2);
                            yop[(size_t)pr * Wo + (lane >> 1)] = 0.25f * (prevy + sy2);
                        }
                    } else { prevx = sx2; prevy = sy2; }
                }

                // stage row i into this wave's LDS slice (no barrier needed)
                myA[lane] = vx; myB[lane] = vy;
                if (lane < HALO) { myA[64 + lane] = hxv; myB[64 + lane] = hyv; }

                // issue loads for row i+1
                {
                    const int rr = min(r0 + i + 1, H - 1);
                    const float* rx = xp + (size_t)rr * W;
                    const float* ry = yp + (size_t)rr * W;
                    vx = rx[cl]; vy = ry[cl];
                    if (lane < HALO) { hxv = rx[chalo]; hyv = ry[chalo]; }
                }

                // horizontal 11-tap conv from 6 named float2 LDS loads
                const v2f* pa = (const v2f*)&myA[e];
                const v2f* pb = (const v2f*)&myB[e];
                const v2f qa0 = pa[0], qa1 = pa[1], qa2 = pa[2],
                          qa3 = pa[3], qa4 = pa[4], qa5 = pa[5];
                const v2f qb0 = pb[0], qb1 = pb[1], qb2 = pb[2],
                          qb3 = pb[3], qb4 = pb[4], qb5 = pb[5];
                v2f hm = {0.f, 0.f}, hs = {0.f, 0.f};
                float hc = 0.f;
                HT(qa0, qb0, w2_0,  w2_1)
                HT(qa1, qb1, w2_2,  w2_3)
                HT(qa2, qb2, w2_4,  w2_5)
                HT(qa3, qb3, w2_6,  w2_7)
                HT(qa4, qb4, w2_8,  w2_9)
                HT(qa5, qb5, w2_10, w2_11)

                // shift in row i (renamed away under the unroll)
                Hm0=Hm1; Hm1=Hm2; Hm2=Hm3; Hm3=Hm4; Hm4=Hm5; Hm5=Hm6;
                Hm6=Hm7; Hm7=Hm8; Hm8=Hm9; Hm9=Hm10; Hm10=hm;
                Hs0=Hs1; Hs1=Hs2; Hs2=Hs3; Hs3=Hs4; Hs4=Hs5; Hs5=Hs6;
                Hs6=Hs7; Hs7=Hs8; Hs8=Hs9; Hs9=Hs10; Hs10=hs;
                Hc0=Hc1; Hc1=Hc2; Hc2=Hc3; Hc3=Hc4; Hc4=Hc5; Hc5=Hc6;
                Hc6=Hc7; Hc7=Hc8; Hc8=Hc9; Hc9=Hc10; Hc10=hc;

                // output row o = i-10: slot j holds rows o..o+10
                const int o = i - HALO;
                if (o >= 0 && o < n_out && colvalid) {
                    v2f vm = Hm0*G0; vm += Hm1*G1; vm += Hm2*G2; vm += Hm3*G3;
                    vm += Hm4*G4; vm += Hm5*G5; vm += Hm6*G6; vm += Hm7*G7;
                    vm += Hm8*G8; vm += Hm9*G9; vm += Hm10*G10;
                    v2f vs = Hs0*G0; vs += Hs1*G1; vs += Hs2*G2; vs += Hs3*G3;
                    vs += Hs4*G4; vs += Hs5*G5; vs += Hs6*G6; vs += Hs7*G7;
                    vs += Hs8*G8; vs += Hs9*G9; vs += Hs10*G10;
                    float vc = Hc0*G0; vc += Hc1*G1; vc += Hc2*G2; vc += Hc3*G3;
                    vc += Hc4*G4; vc += Hc5*G5; vc += Hc6*G6; vc += Hc7*G7;
                    vc += Hc8*G8; vc += Hc9*G9; vc += Hc10*G10;

                    const float mx = vm.x, my = vm.y;
                    const float mu_x2 = mx * mx, mu_y2 = my * my, mu_xy = mx * my;
                    const float sxq = vs.x - mu_x2, syq = vs.y - mu_y2, sxyv = vc - mu_xy;
                    const float c1 = 1e-4f, c2 = 9e-4f;
                    const float cs = (2.f * sxyv + c2) * __builtin_amdgcn_rcpf(sxq + syq + c2);
                    const float ssim = (2.f * mu_xy + c1) * __builtin_amdgcn_rcpf(mu_x2 + mu_y2 + c1) * cs;
                    ssim_sum += ssim;
                    cs_sum += cs;
                }
            }
        }
    }

    // wave-local reduction + one atomic pair per wave
#pragma unroll
    for (int off = 32; off > 0; off >>= 1) {
        ssim_sum += __shfl_down(ssim_sum, off, 64);
        cs_sum   += __shfl_down(cs_sum,   off, 64);
    }
    if (lane == 0) {
        atomicAdd(&acc[nc * 2 + 0], ssim_sum);
        atomicAdd(&acc[nc * 2 + 1], cs_sum);
    }
}

// Combine the 5 scales: prod_s val_s^{w_s}, mean over the 48 (n,c) pairs.
__global__ void finalize_kernel(const float* __restrict__ acc,
                                const float* __restrict__ weights,
                                float* __restrict__ out)
{
    int t = threadIdx.x;  // 64 threads
    float v = 0.f;
    if (t < 48) {
        float prod = 1.f;
#pragma unroll
        for (int s = 0; s < 5; ++s) {
            int O = (512 >> s) - HALO;
            float inv = 1.f / ((float)O * (float)O);
            float ssim = acc[s * 96 + t * 2 + 0] * inv;
            float cs   = acc[s * 96 + t * 2 + 1] * inv;
            float val = (s < 4) ? fmaxf(cs, 0.f) : ssim;  // mcs[:-1] + [ssim]
            prod *= powf(val, weights[s]);
        }
        v = prod;
    }
#pragma unroll
    for (int off = 32; off > 0; off >>= 1) v += __shfl_down(v, off, 64);
    if (t == 0) out[0] = v * (1.f / 48.f);
}

extern "C" void kernel_launch(void* const* d_in, const int* in_sizes, int n_in,
                              void* d_out, int out_size, void* d_ws, size_t ws_size,
                              hipStream_t stream) {
    const float* x = (const float*)d_in[0];       // (16,3,512,512)
    const float* y = (const float*)d_in[1];       // (16,3,512,512)
    const float* weights = (const float*)d_in[3]; // (5,)
    float* out = (float*)d_out;
    float* ws = (float*)d_ws;

    // workspace layout (floats):
    //   [0,480)   : acc[5 scales][48 nc][2]   (ssim_sum, cs_sum)
    //   [512, ..) : downsampled pyramid x/y per scale
    float* acc = ws;
    float* xs1 = ws + 512;
    float* ys1 = xs1 + (size_t)48 * 256 * 256;
    float* xs2 = ys1 + (size_t)48 * 256 * 256;
    float* ys2 = xs2 + (size_t)48 * 128 * 128;
    float* xs3 = ys2 + (size_t)48 * 128 * 128;
    float* ys3 = xs3 + (size_t)48 * 64 * 64;
    float* xs4 = ys3 + (size_t)48 * 64 * 64;
    float* ys4 = xs4 + (size_t)48 * 32 * 32;

    hipMemsetAsync(acc, 0, 480 * sizeof(float), stream);

    dim3 blk(256);
    // grid: (col strips of 64, row chunks of 4*ROWS, nc); 4 indep waves/block
    ssim_wave_kernel<<<dim3(8, 2, 48), blk, 0, stream>>>(x, y, xs1, ys1, acc + 0 * 96, 512, 512, 64, 1);
    ssim_wave_kernel<<<dim3(4, 2, 48), blk, 0, stream>>>(xs1, ys1, xs2, ys2, acc + 1 * 96, 256, 256, 32, 1);
    ssim_wave_kernel<<<dim3(2, 2, 48), blk, 0, stream>>>(xs2, ys2, xs3, ys3, acc + 2 * 96, 128, 128, 16, 1);
    ssim_wave_kernel<<<dim3(1, 2, 48), blk, 0, stream>>>(xs3, ys3, xs4, ys4, acc + 3 * 96, 64, 64, 8, 1);
    ssim_wave_kernel<<<dim3(1, 1, 48), blk, 0, stream>>>(xs4, ys4, nullptr, nullptr, acc + 4 * 96, 32, 32, 8, 0);

    finalize_kernel<<<dim3(1), dim3(64), 0, stream>>>(acc, weights, out);
}